// Round 3
// baseline (1084.273 us; speedup 1.0000x reference)
//
#include <hip/hip_runtime.h>

#define FIN 512
#define FMID 16
#define FOUT 64

// bucket = dst >> 6 : 64 nodes per bucket; record = (src<<6) | (dst&63)
#define BBITS 6
#define BSZ 64
#define NB_MAX 2048
#define NWG_SC 256  // workgroups for count/scatter passes

// ---------- bucket count: LDS histogram per wg, one global atomic per bucket ----------
__global__ __launch_bounds__(256) void k_bcount(const int* __restrict__ dst,
                                                int* __restrict__ bcnt,
                                                int E, int nb, int chunk) {
  __shared__ int cnt[NB_MAX];
  const int t = threadIdx.x;
  for (int i = t; i < nb; i += 256) cnt[i] = 0;
  __syncthreads();
  const int beg = blockIdx.x * chunk;
  const int end = min(beg + chunk, E);
  for (int e = beg + t; e < end; e += 256) atomicAdd(&cnt[dst[e] >> BBITS], 1);
  __syncthreads();
  for (int i = t; i < nb; i += 256) {
    int c = cnt[i];
    if (c) atomicAdd(&bcnt[i], c);
  }
}

// ---------- exclusive scan of bcnt[nb] -> boff, bcur (single workgroup) ----------
__global__ __launch_bounds__(256) void k_bscan(const int* __restrict__ bcnt,
                                               int* __restrict__ boff,
                                               int* __restrict__ bcur, int nb) {
  __shared__ int part[256];
  const int t = threadIdx.x;
  const int PER = 8;  // 256*8 = 2048 >= nb
  int v[PER], s = 0;
#pragma unroll
  for (int u = 0; u < PER; ++u) {
    int idx = t * PER + u;
    v[u] = (idx < nb) ? bcnt[idx] : 0;
    s += v[u];
  }
  part[t] = s;
  __syncthreads();
  for (int off = 1; off < 256; off <<= 1) {
    int x = (t >= off) ? part[t - off] : 0;
    __syncthreads();
    part[t] += x;
    __syncthreads();
  }
  int run = part[t] - s;  // exclusive prefix
#pragma unroll
  for (int u = 0; u < PER; ++u) {
    int idx = t * PER + u;
    if (idx < nb) { boff[idx] = run; bcur[idx] = run; }
    run += v[u];
  }
}

// ---------- scatter: per-wg LDS hist -> claim contiguous runs -> ranked writes ----------
__global__ __launch_bounds__(256) void k_bscatter(const int* __restrict__ src,
                                                  const int* __restrict__ dst,
                                                  int* __restrict__ bcur,
                                                  unsigned* __restrict__ rec,
                                                  int E, int nb, int chunk) {
  __shared__ int cnt[NB_MAX];
  __shared__ int goff[NB_MAX];
  const int t = threadIdx.x;
  for (int i = t; i < nb; i += 256) cnt[i] = 0;
  __syncthreads();
  const int beg = blockIdx.x * chunk;
  const int end = min(beg + chunk, E);
  for (int e = beg + t; e < end; e += 256) atomicAdd(&cnt[dst[e] >> BBITS], 1);
  __syncthreads();
  for (int i = t; i < nb; i += 256) {
    int c = cnt[i];
    goff[i] = c ? atomicAdd(&bcur[i], c) : 0;
  }
  __syncthreads();
  for (int i = t; i < nb; i += 256) cnt[i] = 0;
  __syncthreads();
  for (int e = beg + t; e < end; e += 256) {
    int d = dst[e];
    int b = d >> BBITS;
    int r = atomicAdd(&cnt[b], 1);
    rec[goff[b] + r] = ((unsigned)src[e] << BBITS) | (unsigned)(d & (BSZ - 1));
  }
}

// ---------- degrees -> dis from bucketed records (one wg per bucket) ----------
__global__ __launch_bounds__(256) void k_bdis(const unsigned* __restrict__ rec,
                                              const int* __restrict__ boff,
                                              const int* __restrict__ bcnt,
                                              float* __restrict__ dis, int N) {
  __shared__ int cnt[BSZ];
  const int t = threadIdx.x;
  const int b = blockIdx.x;
  if (t < BSZ) cnt[t] = 0;
  __syncthreads();
  const int beg = boff[b], end = beg + bcnt[b];
  for (int i = beg + t; i < end; i += 256) atomicAdd(&cnt[rec[i] & (BSZ - 1)], 1);
  __syncthreads();
  if (t < BSZ) {
    int node = b * BSZ + t;
    if (node < N) dis[node] = rsqrtf(1.0f + (float)cnt[t]);  // +1 self-loop
  }
}

// ---------- h = x @ W1 : one thread per node, W1 wave-uniform (scalar loads) ----------
__global__ __launch_bounds__(256) void k_gemm1(const float* __restrict__ x,
                                               const float* __restrict__ W1,
                                               float* __restrict__ h, int n) {
  int node = blockIdx.x * 256 + threadIdx.x;
  if (node >= n) return;
  const float4* xr = (const float4*)(x + (size_t)node * FIN);
  float acc[FMID];
#pragma unroll
  for (int j = 0; j < FMID; ++j) acc[j] = 0.f;
  for (int k4 = 0; k4 < FIN / 4; ++k4) {
    float4 xv = xr[k4];
    const float* wr = W1 + k4 * 4 * FMID;  // uniform across lanes -> s_load
#pragma unroll
    for (int j = 0; j < FMID; ++j) acc[j] += xv.x * wr[j];
#pragma unroll
    for (int j = 0; j < FMID; ++j) acc[j] += xv.y * wr[FMID + j];
#pragma unroll
    for (int j = 0; j < FMID; ++j) acc[j] += xv.z * wr[2 * FMID + j];
#pragma unroll
    for (int j = 0; j < FMID; ++j) acc[j] += xv.w * wr[3 * FMID + j];
  }
  float4* hr = (float4*)(h + (size_t)node * FMID);
#pragma unroll
  for (int j4 = 0; j4 < FMID / 4; ++j4)
    hr[j4] = make_float4(acc[4 * j4], acc[4 * j4 + 1], acc[4 * j4 + 2], acc[4 * j4 + 3]);
}

// ---------- propagation: one wg per bucket, LDS fp32 accumulator tile ----------
// out[dst] = dis[dst]*sum_{src->dst} in[src]*dis[src] + in[dst]*dis[dst]^2 (+bias)(relu)
__global__ __launch_bounds__(256) void k_prop(const float* __restrict__ in,
                                              const unsigned* __restrict__ rec,
                                              const int* __restrict__ boff,
                                              const int* __restrict__ bcnt,
                                              const float* __restrict__ dis,
                                              const float* __restrict__ bias,
                                              float* __restrict__ out, int N, int relu) {
  __shared__ float acc[BSZ * FMID];  // 4 KB
  const int t = threadIdx.x;
  const int b = blockIdx.x;
  for (int i = t; i < BSZ * FMID; i += 256) acc[i] = 0.f;
  __syncthreads();
  const int g = t >> 4;      // 16 groups of 16 lanes
  const int j = t & 15;
  const int beg = boff[b], end = beg + bcnt[b];
  int e = beg + g;
  for (; e + 16 < end; e += 32) {  // unroll x2: independent chains
    unsigned r0 = rec[e], r1 = rec[e + 16];
    int s0 = r0 >> BBITS, s1 = r1 >> BBITS;
    float w0 = dis[s0], w1 = dis[s1];
    float v0 = in[(size_t)s0 * FMID + j];
    float v1 = in[(size_t)s1 * FMID + j];
    atomicAdd(&acc[((r0 & (BSZ - 1)) << 4) + j], v0 * w0);
    atomicAdd(&acc[((r1 & (BSZ - 1)) << 4) + j], v1 * w1);
  }
  if (e < end) {
    unsigned r0 = rec[e];
    int s0 = r0 >> BBITS;
    atomicAdd(&acc[((r0 & (BSZ - 1)) << 4) + j], in[(size_t)s0 * FMID + j] * dis[s0]);
  }
  __syncthreads();
  // flush: contiguous 4 KB store (out offset = b*1024 + idx)
  for (int idx = t; idx < BSZ * FMID; idx += 256) {
    int node = (b << BBITS) + (idx >> 4);
    if (node < N) {
      float dd = dis[node];
      float v = acc[idx] * dd + in[(size_t)node * FMID + (idx & 15)] * dd * dd;
      if (bias) v += bias[idx & 15];
      if (relu) v = fmaxf(v, 0.f);
      out[(size_t)node * FMID + (idx & 15)] = v;
    }
  }
}

// ---------- out = log_softmax(a2 @ W2 + b2) : one wave per node ----------
__global__ __launch_bounds__(256) void k_out(const float* __restrict__ a2,
                                             const float* __restrict__ W2,
                                             const float* __restrict__ b2,
                                             float* __restrict__ out, int n) {
  __shared__ float w[FMID * FOUT];  // 4 KB
  for (int idx = threadIdx.x; idx < FMID * FOUT; idx += 256) w[idx] = W2[idx];
  __syncthreads();
  const int lane = threadIdx.x & 63;
  const int node = blockIdx.x * 4 + (threadIdx.x >> 6);
  if (node >= n) return;
  const float* ar = a2 + (size_t)node * FMID;  // wave-uniform -> s_load
  float o = b2[lane];
#pragma unroll
  for (int k = 0; k < FMID; ++k) o += ar[k] * w[k * FOUT + lane];
  float m = o;
#pragma unroll
  for (int off = 32; off >= 1; off >>= 1) m = fmaxf(m, __shfl_xor(m, off));
  float e = __expf(o - m);
  float s = e;
#pragma unroll
  for (int off = 32; off >= 1; off >>= 1) s += __shfl_xor(s, off);
  out[(size_t)node * FOUT + lane] = o - m - __logf(s);
}

// ---------- launch ----------
extern "C" void kernel_launch(void* const* d_in, const int* in_sizes, int n_in,
                              void* d_out, int out_size, void* d_ws, size_t ws_size,
                              hipStream_t stream) {
  const float* x  = (const float*)d_in[0];
  const int* edge = (const int*)d_in[1];
  const float* W1 = (const float*)d_in[2];
  const float* b1 = (const float*)d_in[3];
  const float* W2 = (const float*)d_in[4];
  const float* b2 = (const float*)d_in[5];
  float* out = (float*)d_out;

  const int N = in_sizes[0] / FIN;  // 100000
  const int E = in_sizes[1] / 2;    // 3200000
  const int* src = edge;
  const int* dst = edge + E;

  const int NB = (N + BSZ - 1) / BSZ;       // 1563
  const int NA = (N + 63) & ~63;

  // ws layout (4-byte words):
  // bcnt[NB_MAX] | boff[NB_MAX] | bcur[NB_MAX] | dis[NA] | h[16NA] | a1[16NA] | rec[E]
  int*      bcnt = (int*)d_ws;
  int*      boff = bcnt + NB_MAX;
  int*      bcur = boff + NB_MAX;
  float*    dis  = (float*)(bcur + NB_MAX);
  float*    h    = dis + NA;
  float*    a1   = h + (size_t)16 * NA;
  unsigned* rec  = (unsigned*)(a1 + (size_t)16 * NA);

  const int T = 256;
  const int chunk = (E + NWG_SC - 1) / NWG_SC;

  hipMemsetAsync(bcnt, 0, NB * sizeof(int), stream);
  k_bcount  <<<NWG_SC, T, 0, stream>>>(dst, bcnt, E, NB, chunk);
  k_bscan   <<<1, T, 0, stream>>>(bcnt, boff, bcur, NB);
  k_bscatter<<<NWG_SC, T, 0, stream>>>(src, dst, bcur, rec, E, NB, chunk);
  k_bdis    <<<NB, T, 0, stream>>>(rec, boff, bcnt, dis, N);

  k_gemm1<<<(N + T - 1) / T, T, 0, stream>>>(x, W1, h, N);

  // layer 1: a1 = relu(P h + b1)
  k_prop<<<NB, T, 0, stream>>>(h, rec, boff, bcnt, dis, b1, a1, N, 1);
  // layer 2 propagate first at 16-dim (P(a1 W2) == (P a1) W2); reuse h as a2
  k_prop<<<NB, T, 0, stream>>>(a1, rec, boff, bcnt, dis, nullptr, h, N, 0);

  // transform + log_softmax
  k_out<<<(N + 3) / 4, T, 0, stream>>>(h, W2, b2, out, N);
}

// Round 4
// 1037.294 us; speedup vs baseline: 1.0453x; 1.0453x over previous
//
#include <hip/hip_runtime.h>
#include <hip/hip_fp16.h>

#define FIN 512
#define FMID 16
#define FOUT 64

// bucket = dst >> 6 : 64 nodes per bucket; record = (src<<6) | (dst&63)
#define BBITS 6
#define BSZ 64
#define NB_MAX 2048
#define NWG_SC 128
#define T_SC 512

// ---------- bucket count: LDS histogram per wg, one global atomic per bucket ----------
__global__ __launch_bounds__(T_SC) void k_bcount(const int* __restrict__ dst,
                                                 int* __restrict__ bcnt,
                                                 int E, int nb, int chunk) {
  __shared__ int cnt[NB_MAX];
  const int t = threadIdx.x;
  for (int i = t; i < nb; i += T_SC) cnt[i] = 0;
  __syncthreads();
  const int beg = blockIdx.x * chunk;
  const int end = min(beg + chunk, E);
  const int n4 = (end - beg) >> 2;
  const int4* d4 = (const int4*)(dst + beg);
  for (int i = t; i < n4; i += T_SC) {
    int4 v = d4[i];
    atomicAdd(&cnt[v.x >> BBITS], 1);
    atomicAdd(&cnt[v.y >> BBITS], 1);
    atomicAdd(&cnt[v.z >> BBITS], 1);
    atomicAdd(&cnt[v.w >> BBITS], 1);
  }
  for (int e = beg + (n4 << 2) + t; e < end; e += T_SC) atomicAdd(&cnt[dst[e] >> BBITS], 1);
  __syncthreads();
  for (int i = t; i < nb; i += T_SC) {
    int c = cnt[i];
    if (c) atomicAdd(&bcnt[i], c);
  }
}

// ---------- exclusive scan of bcnt[nb] -> boff, bcur (single workgroup) ----------
__global__ __launch_bounds__(256) void k_bscan(const int* __restrict__ bcnt,
                                               int* __restrict__ boff,
                                               int* __restrict__ bcur, int nb) {
  __shared__ int part[256];
  const int t = threadIdx.x;
  const int PER = 8;  // 256*8 = 2048 >= nb
  int v[PER], s = 0;
#pragma unroll
  for (int u = 0; u < PER; ++u) {
    int idx = t * PER + u;
    v[u] = (idx < nb) ? bcnt[idx] : 0;
    s += v[u];
  }
  part[t] = s;
  __syncthreads();
  for (int off = 1; off < 256; off <<= 1) {
    int x = (t >= off) ? part[t - off] : 0;
    __syncthreads();
    part[t] += x;
    __syncthreads();
  }
  int run = part[t] - s;
#pragma unroll
  for (int u = 0; u < PER; ++u) {
    int idx = t * PER + u;
    if (idx < nb) { boff[idx] = run; bcur[idx] = run; }
    run += v[u];
  }
}

// ---------- scatter: per-wg LDS hist -> claim contiguous runs -> ranked writes ----------
__global__ __launch_bounds__(T_SC) void k_bscatter(const int* __restrict__ src,
                                                   const int* __restrict__ dst,
                                                   int* __restrict__ bcur,
                                                   unsigned* __restrict__ rec,
                                                   int E, int nb, int chunk) {
  __shared__ int cnt[NB_MAX];
  __shared__ int goff[NB_MAX];
  const int t = threadIdx.x;
  for (int i = t; i < nb; i += T_SC) cnt[i] = 0;
  __syncthreads();
  const int beg = blockIdx.x * chunk;
  const int end = min(beg + chunk, E);
  const int n4 = (end - beg) >> 2;
  const int4* d4 = (const int4*)(dst + beg);
  const int4* s4 = (const int4*)(src + beg);
  for (int i = t; i < n4; i += T_SC) {
    int4 v = d4[i];
    atomicAdd(&cnt[v.x >> BBITS], 1);
    atomicAdd(&cnt[v.y >> BBITS], 1);
    atomicAdd(&cnt[v.z >> BBITS], 1);
    atomicAdd(&cnt[v.w >> BBITS], 1);
  }
  for (int e = beg + (n4 << 2) + t; e < end; e += T_SC) atomicAdd(&cnt[dst[e] >> BBITS], 1);
  __syncthreads();
  for (int i = t; i < nb; i += T_SC) {
    int c = cnt[i];
    goff[i] = c ? atomicAdd(&bcur[i], c) : 0;
  }
  __syncthreads();
  for (int i = t; i < nb; i += T_SC) cnt[i] = 0;
  __syncthreads();
  for (int i = t; i < n4; i += T_SC) {
    int4 dv = d4[i];
    int4 sv = s4[i];
#pragma unroll
    for (int u = 0; u < 4; ++u) {
      int d = (&dv.x)[u], s = (&sv.x)[u];
      int b = d >> BBITS;
      int r = atomicAdd(&cnt[b], 1);
      rec[goff[b] + r] = ((unsigned)s << BBITS) | (unsigned)(d & (BSZ - 1));
    }
  }
  for (int e = beg + (n4 << 2) + t; e < end; e += T_SC) {
    int d = dst[e];
    int b = d >> BBITS;
    int r = atomicAdd(&cnt[b], 1);
    rec[goff[b] + r] = ((unsigned)src[e] << BBITS) | (unsigned)(d & (BSZ - 1));
  }
}

// ---------- degrees -> dis from bucketed records (one wg per bucket) ----------
__global__ __launch_bounds__(256) void k_bdis(const unsigned* __restrict__ rec,
                                              const int* __restrict__ boff,
                                              const int* __restrict__ bcnt,
                                              float* __restrict__ dis, int N) {
  __shared__ int cnt[BSZ];
  const int t = threadIdx.x;
  const int b = blockIdx.x;
  if (t < BSZ) cnt[t] = 0;
  __syncthreads();
  const int beg = boff[b], end = beg + bcnt[b];
  for (int i = beg + t; i < end; i += 256) atomicAdd(&cnt[rec[i] & (BSZ - 1)], 1);
  __syncthreads();
  if (t < BSZ) {
    int node = b * BSZ + t;
    if (node < N) dis[node] = rsqrtf(1.0f + (float)cnt[t]);  // +1 self-loop
  }
}

// ---------- hs = (x @ W1) * dis[node], fp16; W1 wave-uniform scalar loads ----------
__global__ __launch_bounds__(256) void k_gemm1(const float* __restrict__ x,
                                               const float* __restrict__ W1,
                                               const float* __restrict__ dis,
                                               __half* __restrict__ hs, int n) {
  int node = blockIdx.x * 256 + threadIdx.x;
  if (node >= n) return;
  const float4* xr = (const float4*)(x + (size_t)node * FIN);
  float acc[FMID];
#pragma unroll
  for (int j = 0; j < FMID; ++j) acc[j] = 0.f;
  for (int k4 = 0; k4 < FIN / 4; ++k4) {
    float4 xv = xr[k4];
    const float* wr = W1 + k4 * 4 * FMID;  // uniform across lanes -> s_load
#pragma unroll
    for (int j = 0; j < FMID; ++j) acc[j] += xv.x * wr[j];
#pragma unroll
    for (int j = 0; j < FMID; ++j) acc[j] += xv.y * wr[FMID + j];
#pragma unroll
    for (int j = 0; j < FMID; ++j) acc[j] += xv.z * wr[2 * FMID + j];
#pragma unroll
    for (int j = 0; j < FMID; ++j) acc[j] += xv.w * wr[3 * FMID + j];
  }
  const float d = dis[node];
  __half tmp[FMID];
#pragma unroll
  for (int j = 0; j < FMID; ++j) tmp[j] = __float2half(acc[j] * d);
  uint4* hout = (uint4*)(hs + (size_t)node * FMID);  // 32B, aligned
  hout[0] = ((const uint4*)tmp)[0];
  hout[1] = ((const uint4*)tmp)[1];
}

// ---------- propagation: one wg per bucket, LDS fp32 tile, fp16 pre-scaled input ----------
// acc[d] = sum_{src->d} in[src]           (in is pre-scaled by dis[src])
// v = dis[d] * (acc[d] + in[d]);  mode1: v = relu(v + bias)*dis[d]  (pre-scale for next layer)
__global__ __launch_bounds__(256) void k_prop(const __half* __restrict__ in,
                                              const unsigned* __restrict__ rec,
                                              const int* __restrict__ boff,
                                              const int* __restrict__ bcnt,
                                              const float* __restrict__ dis,
                                              const float* __restrict__ bias,
                                              __half* __restrict__ out, int N, int mode) {
  __shared__ float acc[BSZ * FMID];  // 4 KB
  const int t = threadIdx.x;
  const int b = blockIdx.x;
  for (int i = t; i < BSZ * FMID; i += 256) acc[i] = 0.f;
  __syncthreads();
  const int g = t >> 4;  // 16 groups of 16 lanes
  const int j = t & 15;
  const int beg = boff[b], end = beg + bcnt[b];
  int e = beg + g;
  for (; e + 48 < end; e += 64) {  // unroll x4: independent chains
    unsigned r0 = rec[e], r1 = rec[e + 16], r2 = rec[e + 32], r3 = rec[e + 48];
    float v0 = __half2float(in[((size_t)(r0 >> BBITS) << 4) + j]);
    float v1 = __half2float(in[((size_t)(r1 >> BBITS) << 4) + j]);
    float v2 = __half2float(in[((size_t)(r2 >> BBITS) << 4) + j]);
    float v3 = __half2float(in[((size_t)(r3 >> BBITS) << 4) + j]);
    atomicAdd(&acc[((r0 & (BSZ - 1)) << 4) + j], v0);
    atomicAdd(&acc[((r1 & (BSZ - 1)) << 4) + j], v1);
    atomicAdd(&acc[((r2 & (BSZ - 1)) << 4) + j], v2);
    atomicAdd(&acc[((r3 & (BSZ - 1)) << 4) + j], v3);
  }
  for (; e < end; e += 16) {
    unsigned r0 = rec[e];
    atomicAdd(&acc[((r0 & (BSZ - 1)) << 4) + j],
              __half2float(in[((size_t)(r0 >> BBITS) << 4) + j]));
  }
  __syncthreads();
  for (int idx = t; idx < BSZ * FMID; idx += 256) {
    int node = (b << BBITS) + (idx >> 4);
    if (node < N) {
      float dd = dis[node];
      float selfv = __half2float(in[((size_t)node << 4) + (idx & 15)]);
      float v = dd * (acc[idx] + selfv);
      if (mode) v = fmaxf(v + bias[idx & 15], 0.f) * dd;  // bias+relu, pre-scale for layer 2
      out[((size_t)node << 4) + (idx & 15)] = __float2half(v);
    }
  }
}

// ---------- out = log_softmax(a2 @ W2 + b2) : one wave per node ----------
__global__ __launch_bounds__(256) void k_out(const __half* __restrict__ a2,
                                             const float* __restrict__ W2,
                                             const float* __restrict__ b2,
                                             float* __restrict__ out, int n) {
  __shared__ float w[FMID * FOUT];  // 4 KB
  for (int idx = threadIdx.x; idx < FMID * FOUT; idx += 256) w[idx] = W2[idx];
  __syncthreads();
  const int lane = threadIdx.x & 63;
  const int node = blockIdx.x * 4 + (threadIdx.x >> 6);
  if (node >= n) return;
  const __half* ar = a2 + ((size_t)node << 4);  // wave-uniform -> scalar loads
  float o = b2[lane];
#pragma unroll
  for (int k = 0; k < FMID; ++k) o += __half2float(ar[k]) * w[k * FOUT + lane];
  float m = o;
#pragma unroll
  for (int off = 32; off >= 1; off >>= 1) m = fmaxf(m, __shfl_xor(m, off));
  float e = __expf(o - m);
  float s = e;
#pragma unroll
  for (int off = 32; off >= 1; off >>= 1) s += __shfl_xor(s, off);
  out[(size_t)node * FOUT + lane] = o - m - __logf(s);
}

// ---------- launch ----------
extern "C" void kernel_launch(void* const* d_in, const int* in_sizes, int n_in,
                              void* d_out, int out_size, void* d_ws, size_t ws_size,
                              hipStream_t stream) {
  const float* x  = (const float*)d_in[0];
  const int* edge = (const int*)d_in[1];
  const float* W1 = (const float*)d_in[2];
  const float* b1 = (const float*)d_in[3];
  const float* W2 = (const float*)d_in[4];
  const float* b2 = (const float*)d_in[5];
  float* out = (float*)d_out;

  const int N = in_sizes[0] / FIN;  // 100000
  const int E = in_sizes[1] / 2;    // 3200000
  const int* src = edge;
  const int* dst = edge + E;

  const int NB = (N + BSZ - 1) / BSZ;  // 1563
  const int NA = (N + 63) & ~63;

  // ws layout (4-byte words):
  // bcnt[NB_MAX] | boff[NB_MAX] | bcur[NB_MAX] | dis[NA] | rec[E] | hs[16NA h] | a1s[16NA h] | a2[16NA h]
  int*      bcnt = (int*)d_ws;
  int*      boff = bcnt + NB_MAX;
  int*      bcur = boff + NB_MAX;
  float*    dis  = (float*)(bcur + NB_MAX);
  unsigned* rec  = (unsigned*)(dis + NA);
  __half*   hs   = (__half*)(rec + E);
  __half*   a1s  = hs + (size_t)16 * NA;
  __half*   a2   = a1s + (size_t)16 * NA;

  const int T = 256;
  const int chunk = (E + NWG_SC - 1) / NWG_SC;

  hipMemsetAsync(bcnt, 0, NB * sizeof(int), stream);
  k_bcount  <<<NWG_SC, T_SC, 0, stream>>>(dst, bcnt, E, NB, chunk);
  k_bscan   <<<1, T, 0, stream>>>(bcnt, boff, bcur, NB);
  k_bscatter<<<NWG_SC, T_SC, 0, stream>>>(src, dst, bcur, rec, E, NB, chunk);
  k_bdis    <<<NB, T, 0, stream>>>(rec, boff, bcnt, dis, N);

  // hs = (x @ W1) * dis  (fp16, 3.2 MB -> fits per-XCD L2)
  k_gemm1<<<(N + T - 1) / T, T, 0, stream>>>(x, W1, dis, hs, N);

  // layer 1: a1s = relu(P_hat hs + b1) * dis   (pre-scaled for layer 2)
  k_prop<<<NB, T, 0, stream>>>(hs, rec, boff, bcnt, dis, b1, a1s, N, 1);
  // layer 2: a2 = P_hat a1s   (then transform by W2 after propagation)
  k_prop<<<NB, T, 0, stream>>>(a1s, rec, boff, bcnt, dis, nullptr, a2, N, 0);

  // out = log_softmax(a2 @ W2 + b2)
  k_out<<<(N + 3) / 4, T, 0, stream>>>(a2, W2, b2, out, N);
}